// Round 1
// baseline (501.944 us; speedup 1.0000x reference)
//
#include <hip/hip_runtime.h>
#include <hip/hip_bf16.h>
#include <math.h>

// CVFusionProposalRefiner on MI355X.
// Pipeline:
//   1) k_transpose: fm [B,C,H,W] -> fmT [B,H,W,C]   (fmT lives in d_out, same size)
//   2) k_prep:      A = Wq@W1a, Bm = Wf@W1b, u = bq@W1a, v = bf@W1b  (ws)
//   3) k_gather:    per-query offsets/softmax + bilinear gather of RAW features
//                   (Wf commutes with bilinear sampling and the S-weighted sum)
//                   -> raw [B*Q,256], cov [B*Q]  (ws)
//   4) k_gemm1:     h = relu(mask*(q@A) + raw@Bm + mask*u + cov*v + b1) -> d_out
//   5) k_gemm2:     out = h@W2 + b2   (in-place on d_out; blocks own full rows)

#define NB 4
#define NQ_PER_B 16384
#define NS 4
#define NQ (NB * NQ_PER_B)      // 65536
#define OFFSET_SCALE 0.05f

__device__ __forceinline__ float dot4(float4 a, float4 b) {
  return a.x * b.x + a.y * b.y + a.z * b.z + a.w * b.w;
}

// ---------------- 1) transpose fm [B,256,128,128] -> fmT [B,128,128,256] ----
__global__ void __launch_bounds__(256) k_transpose(const float* __restrict__ fm,
                                                   float* __restrict__ fmT) {
  __shared__ float tile[128][65];     // [x][c_local]
  const int bid = blockIdx.x;         // B*H*4 = 2048
  const int c0 = (bid & 3) * 64;
  const int y  = (bid >> 2) & 127;
  const int b  = bid >> 9;
  const int t  = threadIdx.x;
  // read rows of fm (contiguous in x), store transposed into LDS
  for (int idx = t; idx < 64 * 128; idx += 256) {
    const int ci = idx >> 7, x = idx & 127;
    tile[x][ci] = fm[(((size_t)(b * 256 + c0 + ci) * 128 + y) << 7) + x];
  }
  __syncthreads();
  // write contiguous in c
  for (int idx = t; idx < 128 * 64; idx += 256) {
    const int x = idx >> 6, cl = idx & 63;
    fmT[(((size_t)(b * 128 + y) * 128 + x) << 8) + c0 + cl] = tile[x][cl];
  }
}

// ---------------- 2) prep: fold Wq/Wf/biases through W1 ---------------------
__global__ void __launch_bounds__(256) k_prep(const float* __restrict__ Wq,
                                              const float* __restrict__ Wf,
                                              const float* __restrict__ W1,
                                              const float* __restrict__ bq,
                                              const float* __restrict__ bf,
                                              float* __restrict__ abM,
                                              float* __restrict__ uvec,
                                              float* __restrict__ vvec) {
  const int blk = blockIdx.x, n = threadIdx.x;
  if (blk < 256) {                      // A row k: (Wq @ W1[:256])[k,n]
    float s = 0.f;
    for (int j = 0; j < 256; ++j) s = fmaf(Wq[blk * 256 + j], W1[j * 256 + n], s);
    abM[blk * 256 + n] = s;
  } else if (blk < 512) {               // Bm row k: (Wf @ W1[256:])[k,n]
    const int k = blk - 256;
    float s = 0.f;
    for (int j = 0; j < 256; ++j) s = fmaf(Wf[k * 256 + j], W1[(256 + j) * 256 + n], s);
    abM[(256 + k) * 256 + n] = s;
  } else {                              // u = bq@W1a, v = bf@W1b
    float su = 0.f, sv = 0.f;
    for (int j = 0; j < 256; ++j) {
      su = fmaf(bq[j], W1[j * 256 + n], su);
      sv = fmaf(bf[j], W1[(256 + j) * 256 + n], sv);
    }
    uvec[n] = su;
    vvec[n] = sv;
  }
}

// ---------------- 3) gather: offsets + softmax + bilinear raw gather --------
#define CORNER(XI, YI, CW)                                                   \
  do {                                                                      \
    const int xi = (XI), yi = (YI);                                         \
    const float cwv = (CW);                                                 \
    if (xi >= 0 && xi < 128 && yi >= 0 && yi < 128) {                       \
      const float cf = wgt * cwv;                                           \
      const float4* p = (const float4*)(fmTb + ((size_t)(yi * 128 + xi) << 8)); \
      const float4 vv = p[lane];                                            \
      acc.x += cf * vv.x; acc.y += cf * vv.y;                               \
      acc.z += cf * vv.z; acc.w += cf * vv.w;                               \
      cv += cf;                                                             \
    }                                                                       \
  } while (0)

__global__ void __launch_bounds__(256) k_gather(
    const float* __restrict__ queries, const float* __restrict__ ref,
    const int* __restrict__ valid, const float* __restrict__ Wo,
    const float* __restrict__ bo, const float* __restrict__ Ww,
    const float* __restrict__ bw, const float* __restrict__ fmT,
    float* __restrict__ raw, float* __restrict__ cov) {
  __shared__ float sWo[8][256];   // transposed: sWo[j][k] = Wo[k*8+j]
  __shared__ float sWw[4][256];
  __shared__ float sb[12];
  const int t = threadIdx.x;
  for (int i = t; i < 2048; i += 256) sWo[i & 7][i >> 3] = Wo[i];
  for (int i = t; i < 1024; i += 256) sWw[i & 3][i >> 2] = Ww[i];
  if (t < 8) sb[t] = bo[t];
  else if (t < 12) sb[t] = bw[t - 8];
  __syncthreads();

  const int lane = t & 63, wv = t >> 6;
  for (int qi = blockIdx.x * 4 + wv; qi < NQ; qi += gridDim.x * 4) {
    float4 acc = {0.f, 0.f, 0.f, 0.f};
    float cv = 0.f;
    if (valid[qi] != 0) {
      const float4 qv = ((const float4*)(queries + (size_t)qi * 256))[lane];
      float part[12];
#pragma unroll
      for (int j = 0; j < 8; ++j)
        part[j] = dot4(qv, *(const float4*)&sWo[j][lane * 4]);
#pragma unroll
      for (int j = 0; j < 4; ++j)
        part[8 + j] = dot4(qv, *(const float4*)&sWw[j][lane * 4]);
#pragma unroll
      for (int off = 1; off < 64; off <<= 1) {
#pragma unroll
        for (int j = 0; j < 12; ++j) part[j] += __shfl_xor(part[j], off, 64);
      }
      float o[8];
#pragma unroll
      for (int j = 0; j < 8; ++j) o[j] = tanhf(part[j] + sb[j]) * OFFSET_SCALE;
      float wl[4];
      float wmax = -1e30f;
#pragma unroll
      for (int j = 0; j < 4; ++j) {
        wl[j] = part[8 + j] + sb[8 + j];
        wmax = fmaxf(wmax, wl[j]);
      }
      float wsum = 0.f;
#pragma unroll
      for (int j = 0; j < 4; ++j) {
        wl[j] = expf(wl[j] - wmax);
        wsum += wl[j];
      }
      const float winv = 1.0f / wsum;
      const float rx = ref[qi * 2], ry = ref[qi * 2 + 1];
      const float* fmTb = fmT + ((size_t)(qi >> 14) << 22);  // b*128*128*256
#pragma unroll
      for (int s = 0; s < 4; ++s) {
        const float wgt = wl[s] * winv;
        const float gx = fminf(fmaxf(rx + o[2 * s], -1.2f), 1.2f);
        const float gy = fminf(fmaxf(ry + o[2 * s + 1], -1.2f), 1.2f);
        const float xf = (gx + 1.0f) * 63.5f;  // (g+1)*0.5*(128-1)
        const float yf = (gy + 1.0f) * 63.5f;
        const float x0f = floorf(xf), y0f = floorf(yf);
        const float wx = xf - x0f, wy = yf - y0f;
        const int x0 = (int)x0f, y0 = (int)y0f;
        CORNER(x0,     y0,     (1.f - wx) * (1.f - wy));
        CORNER(x0 + 1, y0,     wx * (1.f - wy));
        CORNER(x0,     y0 + 1, (1.f - wx) * wy);
        CORNER(x0 + 1, y0 + 1, wx * wy);
      }
    }
    *(float4*)(raw + (size_t)qi * 256 + lane * 4) = acc;
    if (lane == 0) cov[qi] = cv;
  }
}

// ---------------- 4) GEMM1: h = relu([mq|raw] @ [A;Bm] + m*u + cov*v + b1) --
__global__ void __launch_bounds__(256) k_gemm1(
    const float* __restrict__ Qm, const float* __restrict__ raw,
    const float* __restrict__ AB, const int* __restrict__ valid,
    const float* __restrict__ cov, const float* __restrict__ uvec,
    const float* __restrict__ vvec, const float* __restrict__ b1,
    float* __restrict__ Hout) {
  __shared__ float As[8][128];
  __shared__ float Bs[8][132];
  const int t = threadIdx.x;
  const int nblk = blockIdx.x & 1, mblk = blockIdx.x >> 1;
  const int m0 = mblk * 128, n0 = nblk * 128;
  const int arow = m0 + (t >> 1);
  const int acol0 = (t & 1) * 4;
  const float amask = valid[arow] ? 1.0f : 0.0f;
  const int brow0 = t >> 5;
  const int bcol = n0 + (t & 31) * 4;
  const int tx = t & 15, ty = t >> 4;
  float c[8][8] = {};

  for (int k0 = 0; k0 < 512; k0 += 8) {
    const float* asrc = (k0 < 256) ? (Qm + (size_t)arow * 256 + k0 + acol0)
                                   : (raw + (size_t)arow * 256 + (k0 - 256) + acol0);
    float4 a4 = *(const float4*)asrc;
    if (k0 < 256) { a4.x *= amask; a4.y *= amask; a4.z *= amask; a4.w *= amask; }
    As[acol0 + 0][t >> 1] = a4.x;
    As[acol0 + 1][t >> 1] = a4.y;
    As[acol0 + 2][t >> 1] = a4.z;
    As[acol0 + 3][t >> 1] = a4.w;
    const float4 b4 = *(const float4*)(AB + (size_t)(k0 + brow0) * 256 + bcol);
    *(float4*)&Bs[brow0][(t & 31) * 4] = b4;
    __syncthreads();
#pragma unroll
    for (int kk = 0; kk < 8; ++kk) {
      const float4 a0 = *(const float4*)&As[kk][ty * 8];
      const float4 a1 = *(const float4*)&As[kk][ty * 8 + 4];
      const float4 b0 = *(const float4*)&Bs[kk][tx * 8];
      const float4 b1r = *(const float4*)&Bs[kk][tx * 8 + 4];
      const float av[8] = {a0.x, a0.y, a0.z, a0.w, a1.x, a1.y, a1.z, a1.w};
      const float bv[8] = {b0.x, b0.y, b0.z, b0.w, b1r.x, b1r.y, b1r.z, b1r.w};
#pragma unroll
      for (int i = 0; i < 8; ++i)
#pragma unroll
        for (int j = 0; j < 8; ++j) c[i][j] = fmaf(av[i], bv[j], c[i][j]);
    }
    __syncthreads();
  }

  const int ncol0 = n0 + tx * 8;
  const float4 u0 = *(const float4*)(uvec + ncol0);
  const float4 u1 = *(const float4*)(uvec + ncol0 + 4);
  const float4 v0 = *(const float4*)(vvec + ncol0);
  const float4 v1 = *(const float4*)(vvec + ncol0 + 4);
  const float4 g0 = *(const float4*)(b1 + ncol0);
  const float4 g1 = *(const float4*)(b1 + ncol0 + 4);
  const float uu[8] = {u0.x, u0.y, u0.z, u0.w, u1.x, u1.y, u1.z, u1.w};
  const float vv[8] = {v0.x, v0.y, v0.z, v0.w, v1.x, v1.y, v1.z, v1.w};
  const float bb[8] = {g0.x, g0.y, g0.z, g0.w, g1.x, g1.y, g1.z, g1.w};
#pragma unroll
  for (int i = 0; i < 8; ++i) {
    const int row = m0 + ty * 8 + i;
    const float mf = valid[row] ? 1.0f : 0.0f;
    const float cvr = cov[row];
    float r[8];
#pragma unroll
    for (int j = 0; j < 8; ++j)
      r[j] = fmaxf(c[i][j] + mf * uu[j] + cvr * vv[j] + bb[j], 0.0f);
    const float4 w0 = {r[0], r[1], r[2], r[3]};
    const float4 w1 = {r[4], r[5], r[6], r[7]};
    *(float4*)(Hout + (size_t)row * 256 + ncol0) = w0;
    *(float4*)(Hout + (size_t)row * 256 + ncol0 + 4) = w1;
  }
}

// ---------------- 5) GEMM2: out = h @ W2 + b2  (in-place on d_out) ----------
__global__ void __launch_bounds__(256) k_gemm2(float* __restrict__ HO,
                                               const float* __restrict__ W2,
                                               const float* __restrict__ b2) {
  __shared__ float As[8][64];
  __shared__ float Bs[8][260];
  const int t = threadIdx.x;
  const int m0 = blockIdx.x * 64;
  const int tx = t & 31, ty = t >> 5;
  const int amm = t >> 2, ak0 = (t & 3) * 2;
  const int bkk = t >> 5, bn0 = (t & 31) * 4;
  float c[8][8] = {};

  for (int k0 = 0; k0 < 256; k0 += 8) {
    const float2 a2 = *(const float2*)(HO + (size_t)(m0 + amm) * 256 + k0 + ak0);
    As[ak0 + 0][amm] = a2.x;
    As[ak0 + 1][amm] = a2.y;
    const float4 b4a = *(const float4*)(W2 + (size_t)(k0 + bkk) * 256 + bn0);
    const float4 b4b = *(const float4*)(W2 + (size_t)(k0 + bkk) * 256 + 128 + bn0);
    *(float4*)&Bs[bkk][bn0] = b4a;
    *(float4*)&Bs[bkk][128 + bn0] = b4b;
    __syncthreads();
#pragma unroll
    for (int kk = 0; kk < 8; ++kk) {
      const float4 a0 = *(const float4*)&As[kk][ty * 8];
      const float4 a1 = *(const float4*)&As[kk][ty * 8 + 4];
      const float4 b0 = *(const float4*)&Bs[kk][tx * 8];
      const float4 b1r = *(const float4*)&Bs[kk][tx * 8 + 4];
      const float av[8] = {a0.x, a0.y, a0.z, a0.w, a1.x, a1.y, a1.z, a1.w};
      const float bv[8] = {b0.x, b0.y, b0.z, b0.w, b1r.x, b1r.y, b1r.z, b1r.w};
#pragma unroll
      for (int i = 0; i < 8; ++i)
#pragma unroll
        for (int j = 0; j < 8; ++j) c[i][j] = fmaf(av[i], bv[j], c[i][j]);
    }
    __syncthreads();
  }

  const int ncol0 = tx * 8;
  const float4 g0 = *(const float4*)(b2 + ncol0);
  const float4 g1 = *(const float4*)(b2 + ncol0 + 4);
  const float bb[8] = {g0.x, g0.y, g0.z, g0.w, g1.x, g1.y, g1.z, g1.w};
#pragma unroll
  for (int i = 0; i < 8; ++i) {
    const int row = m0 + ty * 8 + i;
    float r[8];
#pragma unroll
    for (int j = 0; j < 8; ++j) r[j] = c[i][j] + bb[j];
    const float4 w0 = {r[0], r[1], r[2], r[3]};
    const float4 w1 = {r[4], r[5], r[6], r[7]};
    *(float4*)(HO + (size_t)row * 256 + ncol0) = w0;
    *(float4*)(HO + (size_t)row * 256 + ncol0 + 4) = w1;
  }
}

extern "C" void kernel_launch(void* const* d_in, const int* in_sizes, int n_in,
                              void* d_out, int out_size, void* d_ws, size_t ws_size,
                              hipStream_t stream) {
  const float* queries = (const float*)d_in[0];
  const float* ref     = (const float*)d_in[1];
  const float* fm      = (const float*)d_in[2];
  const int*   valid   = (const int*)d_in[3];
  const float* Wq = (const float*)d_in[4];
  const float* bq = (const float*)d_in[5];
  const float* Wf = (const float*)d_in[6];
  const float* bf = (const float*)d_in[7];
  const float* Wo = (const float*)d_in[8];
  const float* bo = (const float*)d_in[9];
  const float* Ww = (const float*)d_in[10];
  const float* bw = (const float*)d_in[11];
  const float* W1 = (const float*)d_in[12];
  const float* b1 = (const float*)d_in[13];
  const float* W2 = (const float*)d_in[14];
  const float* b2 = (const float*)d_in[15];
  float* out = (float*)d_out;

  float* ws   = (float*)d_ws;
  float* raw  = ws;                          // 16777216 floats (64 MB)
  float* cov  = ws + 16777216;               // 65536
  float* abM  = ws + 16777216 + 65536;       // 131072
  float* uvec = abM + 131072;                // 256
  float* vvec = uvec + 256;                  // 256

  float* fmT = out;  // d_out triple-duty: fmT -> h -> out (each stage fully overwrites)

  k_transpose<<<2048, 256, 0, stream>>>(fm, fmT);
  k_prep<<<513, 256, 0, stream>>>(Wq, Wf, W1, bq, bf, abM, uvec, vvec);
  k_gather<<<4096, 256, 0, stream>>>(queries, ref, valid, Wo, bo, Ww, bw, fmT, raw, cov);
  k_gemm1<<<1024, 256, 0, stream>>>(queries, raw, abM, valid, cov, uvec, vvec, b1, out);
  k_gemm2<<<1024, 256, 0, stream>>>(out, W2, b2);
}

// Round 2
// 238.349 us; speedup vs baseline: 2.1059x; 2.1059x over previous
//
#include <hip/hip_runtime.h>
#include <hip/hip_bf16.h>
#include <math.h>

// CVFusionProposalRefiner on MI355X — round 2: bf16 MFMA GEMMs.
// Pipeline:
//   1) k_transpose: fm [B,C,H,W] -> fmT [B,H,W,C]   (fmT lives in d_out)
//   2) k_prep:      ABt = (Wq@W1a | Wf@W1b)^T bf16 [256n,512k], W2t bf16 [256n,256k],
//                   u = bq@W1a, v = bf@W1b (fp32)
//   3) k_gather:    offsets/softmax + bilinear gather of RAW features; emits
//                   qraw bf16 [65536,512] = [mask*q | raw], cov fp32
//   4) k_gemm<512,0>: h = relu(qraw@ABt^T + m*u + cov*v + b1) -> bf16, in-place
//                     into qraw[:, :256]  (each block owns full rows)
//   5) k_gemm<256,1>: out = h@W2 + b2 -> fp32 d_out

#define NQ 65536
#define OFFSET_SCALE 0.05f

typedef __bf16 bf16x8 __attribute__((ext_vector_type(8)));
typedef float f32x4 __attribute__((ext_vector_type(4)));

__device__ __forceinline__ float dot4(float4 a, float4 b) {
  return a.x * b.x + a.y * b.y + a.z * b.z + a.w * b.w;
}

__device__ __forceinline__ ushort f2bf(float f) {
  union { float f; unsigned u; } v; v.f = f;
  unsigned r = v.u + 0x7FFFu + ((v.u >> 16) & 1u);   // RNE
  return (ushort)(r >> 16);
}

__device__ __forceinline__ void gload16(const void* g, void* s) {
  __builtin_amdgcn_global_load_lds(
      (const __attribute__((address_space(1))) void*)g,
      (__attribute__((address_space(3))) void*)s, 16, 0, 0);
}

// ---------------- 1) transpose fm [B,256,128,128] -> fmT [B,128,128,256] ----
__global__ void __launch_bounds__(256) k_transpose(const float* __restrict__ fm,
                                                   float* __restrict__ fmT) {
  __shared__ float tile[128][65];
  const int bid = blockIdx.x;         // B*H*4 = 2048
  const int c0 = (bid & 3) * 64;
  const int y  = (bid >> 2) & 127;
  const int b  = bid >> 9;
  const int t  = threadIdx.x;
  for (int idx = t; idx < 64 * 128; idx += 256) {
    const int ci = idx >> 7, x = idx & 127;
    tile[x][ci] = fm[(((size_t)(b * 256 + c0 + ci) * 128 + y) << 7) + x];
  }
  __syncthreads();
  for (int idx = t; idx < 128 * 64; idx += 256) {
    const int x = idx >> 6, cl = idx & 63;
    fmT[(((size_t)(b * 128 + y) * 128 + x) << 8) + c0 + cl] = tile[x][cl];
  }
}

// ---------------- 2) prep: fold Wq/Wf through W1, transpose, bf16 ----------
__global__ void __launch_bounds__(256) k_prep(const float* __restrict__ Wq,
                                              const float* __restrict__ Wf,
                                              const float* __restrict__ W1,
                                              const float* __restrict__ W2,
                                              const float* __restrict__ bq,
                                              const float* __restrict__ bf,
                                              ushort* __restrict__ ABt,
                                              ushort* __restrict__ W2t,
                                              float* __restrict__ uvec,
                                              float* __restrict__ vvec) {
  const int blk = blockIdx.x, n = threadIdx.x;
  if (blk < 256) {                      // ABt[n][k] = (Wq@W1a)[k,n], k = blk
    float s = 0.f;
    for (int j = 0; j < 256; ++j) s = fmaf(Wq[blk * 256 + j], W1[j * 256 + n], s);
    ABt[(size_t)n * 512 + blk] = f2bf(s);
  } else if (blk < 512) {               // ABt[n][256+k] = (Wf@W1b)[k,n]
    const int k = blk - 256;
    float s = 0.f;
    for (int j = 0; j < 256; ++j) s = fmaf(Wf[k * 256 + j], W1[(256 + j) * 256 + n], s);
    ABt[(size_t)n * 512 + 256 + k] = f2bf(s);
  } else if (blk == 512) {              // u = bq@W1a, v = bf@W1b
    float su = 0.f, sv = 0.f;
    for (int j = 0; j < 256; ++j) {
      su = fmaf(bq[j], W1[j * 256 + n], su);
      sv = fmaf(bf[j], W1[(256 + j) * 256 + n], sv);
    }
    uvec[n] = su;
    vvec[n] = sv;
  } else {                              // W2t[n][k] = W2[k][n], k = blk-513
    const int k = blk - 513;
    W2t[(size_t)n * 256 + k] = f2bf(W2[(size_t)k * 256 + n]);
  }
}

// ---------------- 3) gather: offsets + softmax + bilinear raw gather --------
#define CORNER(XI, YI, CW)                                                   \
  do {                                                                      \
    const int xi = (XI), yi = (YI);                                         \
    const float cwv = (CW);                                                 \
    if (xi >= 0 && xi < 128 && yi >= 0 && yi < 128) {                       \
      const float cf = wgt * cwv;                                           \
      const float4* p = (const float4*)(fmTb + ((size_t)(yi * 128 + xi) << 8)); \
      const float4 vv = p[lane];                                            \
      acc.x += cf * vv.x; acc.y += cf * vv.y;                               \
      acc.z += cf * vv.z; acc.w += cf * vv.w;                               \
      cv += cf;                                                             \
    }                                                                       \
  } while (0)

__global__ void __launch_bounds__(256) k_gather(
    const float* __restrict__ queries, const float* __restrict__ ref,
    const int* __restrict__ valid, const float* __restrict__ Wo,
    const float* __restrict__ bo, const float* __restrict__ Ww,
    const float* __restrict__ bw, const float* __restrict__ fmT,
    ushort* __restrict__ qraw, float* __restrict__ cov) {
  __shared__ float sWo[8][256];
  __shared__ float sWw[4][256];
  __shared__ float sb[12];
  const int t = threadIdx.x;
  for (int i = t; i < 2048; i += 256) sWo[i & 7][i >> 3] = Wo[i];
  for (int i = t; i < 1024; i += 256) sWw[i & 3][i >> 2] = Ww[i];
  if (t < 8) sb[t] = bo[t];
  else if (t < 12) sb[t] = bw[t - 8];
  __syncthreads();

  const int lane = t & 63, wv = t >> 6;
  for (int qi = blockIdx.x * 4 + wv; qi < NQ; qi += gridDim.x * 4) {
    float4 acc = {0.f, 0.f, 0.f, 0.f};
    float cv = 0.f;
    ushort4 qh = {0, 0, 0, 0};
    if (valid[qi] != 0) {
      const float4 qv = ((const float4*)(queries + (size_t)qi * 256))[lane];
      qh.x = f2bf(qv.x); qh.y = f2bf(qv.y); qh.z = f2bf(qv.z); qh.w = f2bf(qv.w);
      float part[12];
#pragma unroll
      for (int j = 0; j < 8; ++j)
        part[j] = dot4(qv, *(const float4*)&sWo[j][lane * 4]);
#pragma unroll
      for (int j = 0; j < 4; ++j)
        part[8 + j] = dot4(qv, *(const float4*)&sWw[j][lane * 4]);
#pragma unroll
      for (int off = 1; off < 64; off <<= 1) {
#pragma unroll
        for (int j = 0; j < 12; ++j) part[j] += __shfl_xor(part[j], off, 64);
      }
      float o[8];
#pragma unroll
      for (int j = 0; j < 8; ++j) o[j] = tanhf(part[j] + sb[j]) * OFFSET_SCALE;
      float wl[4];
      float wmax = -1e30f;
#pragma unroll
      for (int j = 0; j < 4; ++j) {
        wl[j] = part[8 + j] + sb[8 + j];
        wmax = fmaxf(wmax, wl[j]);
      }
      float wsum = 0.f;
#pragma unroll
      for (int j = 0; j < 4; ++j) {
        wl[j] = expf(wl[j] - wmax);
        wsum += wl[j];
      }
      const float winv = 1.0f / wsum;
      const float rx = ref[qi * 2], ry = ref[qi * 2 + 1];
      const float* fmTb = fmT + ((size_t)(qi >> 14) << 22);
#pragma unroll
      for (int s = 0; s < 4; ++s) {
        const float wgt = wl[s] * winv;
        const float gx = fminf(fmaxf(rx + o[2 * s], -1.2f), 1.2f);
        const float gy = fminf(fmaxf(ry + o[2 * s + 1], -1.2f), 1.2f);
        const float xf = (gx + 1.0f) * 63.5f;
        const float yf = (gy + 1.0f) * 63.5f;
        const float x0f = floorf(xf), y0f = floorf(yf);
        const float wx = xf - x0f, wy = yf - y0f;
        const int x0 = (int)x0f, y0 = (int)y0f;
        CORNER(x0,     y0,     (1.f - wx) * (1.f - wy));
        CORNER(x0 + 1, y0,     wx * (1.f - wy));
        CORNER(x0,     y0 + 1, (1.f - wx) * wy);
        CORNER(x0 + 1, y0 + 1, wx * wy);
      }
    }
    ushort4 rh;
    rh.x = f2bf(acc.x); rh.y = f2bf(acc.y); rh.z = f2bf(acc.z); rh.w = f2bf(acc.w);
    *(ushort4*)(qraw + (size_t)qi * 512 + lane * 4) = qh;           // masked q half
    *(ushort4*)(qraw + (size_t)qi * 512 + 256 + lane * 4) = rh;     // raw half
    if (lane == 0) cov[qi] = cv;
  }
}

// ---------------- 4/5) bf16 MFMA GEMM, tile 128x256, 8 waves of 64x64 ------
// A: [M, lda=512] bf16 (first K cols used). Bt: [256, K] bf16.
// MODE 0: h = relu(C + mf*u + cov*v + b1) -> bf16 into hout[row*512+col] (in-place A)
// MODE 1: out = C + b2 -> fp32 fout[row*256+col]
template <int K, int MODE>
__global__ void __launch_bounds__(512, 4) k_gemm(
    const ushort* Ag, const ushort* __restrict__ Btg,
    const int* __restrict__ valid, const float* __restrict__ cov,
    const float* __restrict__ uvec, const float* __restrict__ vvec,
    const float* __restrict__ bias, ushort* hout, float* __restrict__ fout) {
  __shared__ ushort As[128 * 32];     // 8 KB
  __shared__ ushort Bs[256 * 32];     // 16 KB
  const int t = threadIdx.x;
  const int m0 = blockIdx.x * 128;
  const int w = t >> 6, lane = t & 63;
  const int wm = w >> 2, wn = w & 3;          // wave grid 2m x 4n, 64x64 each
  const int lr = lane & 15, lg = lane >> 4;

  const int srow = t >> 2, scol = (t & 3) * 8;
  const ushort* ag  = Ag  + (size_t)(m0 + srow) * 512 + scol;
  const ushort* bg0 = Btg + (size_t)srow * K + scol;
  const ushort* bg1 = Btg + (size_t)(128 + srow) * K + scol;
  ushort* la  = As + t * 8;
  ushort* lb0 = Bs + t * 8;
  ushort* lb1 = Bs + 4096 + t * 8;

  f32x4 acc[4][4] = {};

  for (int k0 = 0; k0 < K; k0 += 32) {
    __syncthreads();
    gload16(ag + k0, la);
    gload16(bg0 + k0, lb0);
    gload16(bg1 + k0, lb1);
    __syncthreads();                 // compiler drains vmcnt(0) before barrier
    bf16x8 af[4], bfr[4];
#pragma unroll
    for (int m = 0; m < 4; ++m)
      af[m] = *(const bf16x8*)(As + (wm * 64 + m * 16 + lr) * 32 + lg * 8);
#pragma unroll
    for (int n = 0; n < 4; ++n)
      bfr[n] = *(const bf16x8*)(Bs + (wn * 64 + n * 16 + lr) * 32 + lg * 8);
#pragma unroll
    for (int m = 0; m < 4; ++m)
#pragma unroll
      for (int n = 0; n < 4; ++n)
        acc[m][n] = __builtin_amdgcn_mfma_f32_16x16x32_bf16(af[m], bfr[n], acc[m][n], 0, 0, 0);
  }

  if (MODE == 0) {
    float uu[4], vv[4], bb[4];
#pragma unroll
    for (int n = 0; n < 4; ++n) {
      const int col = wn * 64 + n * 16 + lr;
      uu[n] = uvec[col]; vv[n] = vvec[col]; bb[n] = bias[col];
    }
#pragma unroll
    for (int m = 0; m < 4; ++m)
#pragma unroll
      for (int j = 0; j < 4; ++j) {
        const int row = m0 + wm * 64 + m * 16 + lg * 4 + j;
        const float mf = valid[row] ? 1.0f : 0.0f;
        const float cvr = cov[row];
#pragma unroll
        for (int n = 0; n < 4; ++n) {
          float r = acc[m][n][j] + mf * uu[n] + cvr * vv[n] + bb[n];
          r = fmaxf(r, 0.0f);
          hout[(size_t)row * 512 + wn * 64 + n * 16 + lr] = f2bf(r);
        }
      }
  } else {
    float bb[4];
#pragma unroll
    for (int n = 0; n < 4; ++n) bb[n] = bias[wn * 64 + n * 16 + lr];
#pragma unroll
    for (int m = 0; m < 4; ++m)
#pragma unroll
      for (int j = 0; j < 4; ++j) {
        const int row = m0 + wm * 64 + m * 16 + lg * 4 + j;
#pragma unroll
        for (int n = 0; n < 4; ++n)
          fout[(size_t)row * 256 + wn * 64 + n * 16 + lr] = acc[m][n][j] + bb[n];
      }
  }
}

extern "C" void kernel_launch(void* const* d_in, const int* in_sizes, int n_in,
                              void* d_out, int out_size, void* d_ws, size_t ws_size,
                              hipStream_t stream) {
  const float* queries = (const float*)d_in[0];
  const float* ref     = (const float*)d_in[1];
  const float* fm      = (const float*)d_in[2];
  const int*   valid   = (const int*)d_in[3];
  const float* Wq = (const float*)d_in[4];
  const float* bq = (const float*)d_in[5];
  const float* Wf = (const float*)d_in[6];
  const float* bf = (const float*)d_in[7];
  const float* Wo = (const float*)d_in[8];
  const float* bo = (const float*)d_in[9];
  const float* Ww = (const float*)d_in[10];
  const float* bw = (const float*)d_in[11];
  const float* W1 = (const float*)d_in[12];
  const float* b1 = (const float*)d_in[13];
  const float* W2 = (const float*)d_in[14];
  const float* b2 = (const float*)d_in[15];
  float* out = (float*)d_out;

  // workspace layout (bytes): qraw 67108864 | cov 262144 | ABt 262144 | W2t 131072 | u,v 2048
  char* ws = (char*)d_ws;
  ushort* qraw = (ushort*)ws;                         // [65536, 512] bf16
  float*  cov  = (float*)(ws + 67108864);             // [65536]
  ushort* ABt  = (ushort*)(ws + 67108864 + 262144);   // [256, 512] bf16
  ushort* W2t  = (ushort*)(ws + 67108864 + 524288);   // [256, 256] bf16
  float*  uvec = (float*)(ws + 67108864 + 655360);
  float*  vvec = uvec + 256;

  float* fmT = out;   // d_out double-duty: fmT (gather input) then final out

  k_transpose<<<2048, 256, 0, stream>>>(fm, fmT);
  k_prep<<<769, 256, 0, stream>>>(Wq, Wf, W1, W2, bq, bf, ABt, W2t, uvec, vvec);
  k_gather<<<4096, 256, 0, stream>>>(queries, ref, valid, Wo, bo, Ww, bw, fmT, qraw, cov);
  k_gemm<512, 0><<<512, 512, 0, stream>>>(qraw, ABt, valid, cov, uvec, vvec, b1, qraw, nullptr);
  k_gemm<256, 1><<<512, 512, 0, stream>>>(qraw, W2t, valid, cov, uvec, vvec, b2, nullptr, out);
}

// Round 3
// 188.437 us; speedup vs baseline: 2.6637x; 1.2649x over previous
//
#include <hip/hip_runtime.h>
#include <hip/hip_bf16.h>
#include <math.h>

// CVFusionProposalRefiner on MI355X — round 3: latency-split gather.
// Pipeline:
//   1) k_transpose: fm [B,C,H,W] f32 -> fmT [B,H,W,C] bf16   (in d_out tail-safe)
//   2) k_prep:      ABt bf16 [256,512], W2t bf16 [256,256], u/v fp32
//   3) k_proj:      proj[65536,16] f32 = q@[Wo|Ww]+bias (fp32 VALU), plus
//                   masked bf16 q -> qraw[:, :256]
//   4) k_gather:    offsets/softmax from proj + bilinear bf16 gather ->
//                   qraw[:, 256:], cov.  XCD<->batch partitioned.
//   5) k_gemm<512,0>: h = relu(qraw@ABt^T + m*u + cov*v + b1) -> qraw[:, :256]
//   6) k_gemm<256,1>: out = h@W2t^T + b2 -> fp32 d_out

#define NQ 65536
#define OFFSET_SCALE 0.05f

typedef __bf16 bf16x8 __attribute__((ext_vector_type(8)));
typedef float f32x4 __attribute__((ext_vector_type(4)));
typedef unsigned short ushort8_t __attribute__((ext_vector_type(8)));

__device__ __forceinline__ float dot4(float4 a, float4 b) {
  return a.x * b.x + a.y * b.y + a.z * b.z + a.w * b.w;
}

__device__ __forceinline__ ushort f2bf(float f) {
  union { float f; unsigned u; } v; v.f = f;
  unsigned r = v.u + 0x7FFFu + ((v.u >> 16) & 1u);   // RNE
  return (ushort)(r >> 16);
}

__device__ __forceinline__ float bf2f(ushort u) {
  union { unsigned u; float f; } v; v.u = ((unsigned)u) << 16;
  return v.f;
}

__device__ __forceinline__ void gload16(const void* g, void* s) {
  __builtin_amdgcn_global_load_lds(
      (const __attribute__((address_space(1))) void*)g,
      (__attribute__((address_space(3))) void*)s, 16, 0, 0);
}

// ---------------- 1) transpose fm [B,256,128,128] f32 -> fmT [B,H,W,256] bf16
__global__ void __launch_bounds__(256) k_transpose(const float* __restrict__ fm,
                                                   ushort* __restrict__ fmT) {
  __shared__ float tile[128][65];
  const int bid = blockIdx.x;         // B*H*4 = 2048
  const int c0 = (bid & 3) * 64;
  const int y  = (bid >> 2) & 127;
  const int b  = bid >> 9;
  const int t  = threadIdx.x;
  for (int idx = t; idx < 64 * 128; idx += 256) {
    const int ci = idx >> 7, x = idx & 127;
    tile[x][ci] = fm[(((size_t)(b * 256 + c0 + ci) * 128 + y) << 7) + x];
  }
  __syncthreads();
  for (int idx = t; idx < 128 * 16; idx += 256) {
    const int x = idx >> 4, cg = idx & 15;
    ushort4 o;
    o.x = f2bf(tile[x][cg * 4 + 0]);
    o.y = f2bf(tile[x][cg * 4 + 1]);
    o.z = f2bf(tile[x][cg * 4 + 2]);
    o.w = f2bf(tile[x][cg * 4 + 3]);
    *(ushort4*)(fmT + (((size_t)((b * 128 + y) * 128 + x)) << 8) + c0 + cg * 4) = o;
  }
}

// ---------------- 2) prep: fold Wq/Wf through W1, transpose, bf16 ----------
__global__ void __launch_bounds__(256) k_prep(const float* __restrict__ Wq,
                                              const float* __restrict__ Wf,
                                              const float* __restrict__ W1,
                                              const float* __restrict__ W2,
                                              const float* __restrict__ bq,
                                              const float* __restrict__ bf,
                                              ushort* __restrict__ ABt,
                                              ushort* __restrict__ W2t,
                                              float* __restrict__ uvec,
                                              float* __restrict__ vvec) {
  const int blk = blockIdx.x, n = threadIdx.x;
  if (blk < 256) {                      // ABt[n][k] = (Wq@W1a)[k,n], k = blk
    float s = 0.f;
    for (int j = 0; j < 256; ++j) s = fmaf(Wq[blk * 256 + j], W1[j * 256 + n], s);
    ABt[(size_t)n * 512 + blk] = f2bf(s);
  } else if (blk < 512) {               // ABt[n][256+k] = (Wf@W1b)[k,n]
    const int k = blk - 256;
    float s = 0.f;
    for (int j = 0; j < 256; ++j) s = fmaf(Wf[k * 256 + j], W1[(256 + j) * 256 + n], s);
    ABt[(size_t)n * 512 + 256 + k] = f2bf(s);
  } else if (blk == 512) {              // u = bq@W1a, v = bf@W1b
    float su = 0.f, sv = 0.f;
    for (int j = 0; j < 256; ++j) {
      su = fmaf(bq[j], W1[j * 256 + n], su);
      sv = fmaf(bf[j], W1[(256 + j) * 256 + n], sv);
    }
    uvec[n] = su;
    vvec[n] = sv;
  } else {                              // W2t[n][k] = W2[k][n], k = blk-513
    const int k = blk - 513;
    W2t[(size_t)n * 256 + k] = f2bf(W2[(size_t)k * 256 + n]);
  }
}

// ---------------- 3) proj: 12 projections fp32 + masked bf16 q-half --------
// Lane layout: ql = lane>>4 (query in group of 4), kc = lane&15.
// Lane kc owns channel chunks {kc*4 + i*64 + 0..3}, i=0..3 (stride-64 chunks:
// conflict-free LDS reads + coalesced global loads).
__global__ void __launch_bounds__(256) k_proj(
    const float* __restrict__ queries, const int* __restrict__ valid,
    const float* __restrict__ Wo, const float* __restrict__ bo,
    const float* __restrict__ Ww, const float* __restrict__ bw,
    float* __restrict__ proj, ushort* __restrict__ qraw) {
  __shared__ float sW[12][260];
  __shared__ float sb[12];
  const int t = threadIdx.x;
  for (int i = t; i < 2048; i += 256) sW[i & 7][i >> 3] = Wo[i];
  for (int i = t; i < 1024; i += 256) sW[8 + (i & 3)][i >> 2] = Ww[i];
  if (t < 8) sb[t] = bo[t];
  else if (t < 12) sb[t] = bw[t - 8];
  __syncthreads();

  const int lane = t & 63, wv = t >> 6;
  const int ql = lane >> 4, kc = lane & 15;
  const int qi = blockIdx.x * 16 + wv * 4 + ql;
  const float mf = (valid[qi] != 0) ? 1.0f : 0.0f;

  float4 qv[4];
#pragma unroll
  for (int i = 0; i < 4; ++i)
    qv[i] = *(const float4*)(queries + (size_t)qi * 256 + kc * 4 + i * 64);

  float pr[12];
#pragma unroll
  for (int j = 0; j < 12; ++j) {
    float s = 0.f;
#pragma unroll
    for (int i = 0; i < 4; ++i)
      s += dot4(qv[i], *(const float4*)&sW[j][kc * 4 + i * 64]);
    pr[j] = s;
  }
#pragma unroll
  for (int m = 1; m < 16; m <<= 1) {
#pragma unroll
    for (int j = 0; j < 12; ++j) pr[j] += __shfl_xor(pr[j], m, 64);
  }
  if (kc == 0) {
    float4* pp = (float4*)(proj + (size_t)qi * 16);
    const float4 o0 = {pr[0] + sb[0], pr[1] + sb[1], pr[2] + sb[2],  pr[3] + sb[3]};
    const float4 o1 = {pr[4] + sb[4], pr[5] + sb[5], pr[6] + sb[6],  pr[7] + sb[7]};
    const float4 o2 = {pr[8] + sb[8], pr[9] + sb[9], pr[10] + sb[10], pr[11] + sb[11]};
    pp[0] = o0; pp[1] = o1; pp[2] = o2;
  }
  // masked bf16 q-half
#pragma unroll
  for (int i = 0; i < 4; ++i) {
    ushort4 h;
    h.x = f2bf(qv[i].x * mf); h.y = f2bf(qv[i].y * mf);
    h.z = f2bf(qv[i].z * mf); h.w = f2bf(qv[i].w * mf);
    *(ushort4*)(qraw + (size_t)qi * 512 + kc * 4 + i * 64) = h;
  }
}

// ---------------- 4) gather: offsets + softmax + bilinear bf16 gather ------
#define CORNER(XI, YI, CW)                                                    \
  do {                                                                       \
    const int xi = (XI), yi = (YI);                                          \
    const float cwv = (CW);                                                  \
    if ((unsigned)xi < 128u && (unsigned)yi < 128u) {                        \
      const float cf = wgt * cwv;                                            \
      const ushort4 vv = *(const ushort4*)(fmTb + (((size_t)(yi * 128 + xi)) << 8) + lane * 4); \
      acc.x += cf * bf2f(vv.x); acc.y += cf * bf2f(vv.y);                    \
      acc.z += cf * bf2f(vv.z); acc.w += cf * bf2f(vv.w);                    \
      cv += cf;                                                              \
    }                                                                        \
  } while (0)

__global__ void __launch_bounds__(256) k_gather(
    const float* __restrict__ proj, const float* __restrict__ ref,
    const int* __restrict__ valid, const ushort* __restrict__ fmT,
    ushort* __restrict__ qraw, float* __restrict__ cov) {
  const int t = threadIdx.x, lane = t & 63, wv = t >> 6;
  // XCD<->batch partition: blockIdx%8 = XCD (round-robin dispatch); 2 XCDs/batch.
  const int xcd = blockIdx.x & 7;
  const int b = xcd >> 1;
  const int p = ((blockIdx.x >> 3) << 1) | (xcd & 1);   // 0..511 within batch
  const ushort* fmTb = fmT + ((size_t)b << 22);         // b*128*128*256

#pragma unroll 1
  for (int it = 0; it < 8; ++it) {
    const int qi = b * 16384 + it * 2048 + p * 4 + wv;
    float4 acc = {0.f, 0.f, 0.f, 0.f};
    float cv = 0.f;
    if (valid[qi] != 0) {
      const float* pv = proj + (size_t)qi * 16;
      float o[8];
#pragma unroll
      for (int j = 0; j < 8; ++j) {
        const float x = pv[j];
        const float e = __expf(2.0f * fabsf(x));
        o[j] = copysignf(1.0f - 2.0f / (e + 1.0f), x) * OFFSET_SCALE;
      }
      float wl[4];
      float wmax = -1e30f;
#pragma unroll
      for (int j = 0; j < 4; ++j) {
        wl[j] = pv[8 + j];
        wmax = fmaxf(wmax, wl[j]);
      }
      float wsum = 0.f;
#pragma unroll
      for (int j = 0; j < 4; ++j) {
        wl[j] = __expf(wl[j] - wmax);
        wsum += wl[j];
      }
      const float winv = 1.0f / wsum;
      const float rx = ref[qi * 2], ry = ref[qi * 2 + 1];
#pragma unroll
      for (int s = 0; s < 4; ++s) {
        const float wgt = wl[s] * winv;
        const float gx = fminf(fmaxf(rx + o[2 * s], -1.2f), 1.2f);
        const float gy = fminf(fmaxf(ry + o[2 * s + 1], -1.2f), 1.2f);
        const float xf = (gx + 1.0f) * 63.5f;
        const float yf = (gy + 1.0f) * 63.5f;
        const float x0f = floorf(xf), y0f = floorf(yf);
        const float wx = xf - x0f, wy = yf - y0f;
        const int x0 = (int)x0f, y0 = (int)y0f;
        CORNER(x0,     y0,     (1.f - wx) * (1.f - wy));
        CORNER(x0 + 1, y0,     wx * (1.f - wy));
        CORNER(x0,     y0 + 1, (1.f - wx) * wy);
        CORNER(x0 + 1, y0 + 1, wx * wy);
      }
    }
    ushort4 rh;
    rh.x = f2bf(acc.x); rh.y = f2bf(acc.y); rh.z = f2bf(acc.z); rh.w = f2bf(acc.w);
    *(ushort4*)(qraw + (size_t)qi * 512 + 256 + lane * 4) = rh;
    if (lane == 0) cov[qi] = cv;
  }
}

// ---------------- 5/6) bf16 MFMA GEMM, tile 128x256, 8 waves of 64x64 ------
template <int K, int MODE>
__global__ void __launch_bounds__(512, 4) k_gemm(
    const ushort* Ag, const ushort* __restrict__ Btg,
    const int* __restrict__ valid, const float* __restrict__ cov,
    const float* __restrict__ uvec, const float* __restrict__ vvec,
    const float* __restrict__ bias, ushort* hout, float* __restrict__ fout) {
  __shared__ ushort As[128 * 32];     // 8 KB
  __shared__ ushort Bs[256 * 32];     // 16 KB
  const int t = threadIdx.x;
  const int m0 = blockIdx.x * 128;
  const int w = t >> 6, lane = t & 63;
  const int wm = w >> 2, wn = w & 3;          // wave grid 2m x 4n, 64x64 each
  const int lr = lane & 15, lg = lane >> 4;

  const int srow = t >> 2, scol = (t & 3) * 8;
  const ushort* ag  = Ag  + (size_t)(m0 + srow) * 512 + scol;
  const ushort* bg0 = Btg + (size_t)srow * K + scol;
  const ushort* bg1 = Btg + (size_t)(128 + srow) * K + scol;
  ushort* la  = As + t * 8;
  ushort* lb0 = Bs + t * 8;
  ushort* lb1 = Bs + 4096 + t * 8;

  f32x4 acc[4][4] = {};

  for (int k0 = 0; k0 < K; k0 += 32) {
    __syncthreads();
    gload16(ag + k0, la);
    gload16(bg0 + k0, lb0);
    gload16(bg1 + k0, lb1);
    __syncthreads();
    bf16x8 af[4], bfr[4];
#pragma unroll
    for (int m = 0; m < 4; ++m)
      af[m] = *(const bf16x8*)(As + (wm * 64 + m * 16 + lr) * 32 + lg * 8);
#pragma unroll
    for (int n = 0; n < 4; ++n)
      bfr[n] = *(const bf16x8*)(Bs + (wn * 64 + n * 16 + lr) * 32 + lg * 8);
#pragma unroll
    for (int m = 0; m < 4; ++m)
#pragma unroll
      for (int n = 0; n < 4; ++n)
        acc[m][n] = __builtin_amdgcn_mfma_f32_16x16x32_bf16(af[m], bfr[n], acc[m][n], 0, 0, 0);
  }

  if (MODE == 0) {
    float uu[4], vv[4], bb[4];
#pragma unroll
    for (int n = 0; n < 4; ++n) {
      const int col = wn * 64 + n * 16 + lr;
      uu[n] = uvec[col]; vv[n] = vvec[col]; bb[n] = bias[col];
    }
#pragma unroll
    for (int m = 0; m < 4; ++m)
#pragma unroll
      for (int j = 0; j < 4; ++j) {
        const int row = m0 + wm * 64 + m * 16 + lg * 4 + j;
        const float mf = valid[row] ? 1.0f : 0.0f;
        const float cvr = cov[row];
#pragma unroll
        for (int n = 0; n < 4; ++n) {
          float r = acc[m][n][j] + mf * uu[n] + cvr * vv[n] + bb[n];
          r = fmaxf(r, 0.0f);
          hout[(size_t)row * 512 + wn * 64 + n * 16 + lr] = f2bf(r);
        }
      }
  } else {
    float bb[4];
#pragma unroll
    for (int n = 0; n < 4; ++n) bb[n] = bias[wn * 64 + n * 16 + lr];
#pragma unroll
    for (int m = 0; m < 4; ++m)
#pragma unroll
      for (int j = 0; j < 4; ++j) {
        const int row = m0 + wm * 64 + m * 16 + lg * 4 + j;
#pragma unroll
        for (int n = 0; n < 4; ++n)
          fout[(size_t)row * 256 + wn * 64 + n * 16 + lr] = acc[m][n][j] + bb[n];
      }
  }
}

extern "C" void kernel_launch(void* const* d_in, const int* in_sizes, int n_in,
                              void* d_out, int out_size, void* d_ws, size_t ws_size,
                              hipStream_t stream) {
  const float* queries = (const float*)d_in[0];
  const float* ref     = (const float*)d_in[1];
  const float* fm      = (const float*)d_in[2];
  const int*   valid   = (const int*)d_in[3];
  const float* Wq = (const float*)d_in[4];
  const float* bq = (const float*)d_in[5];
  const float* Wf = (const float*)d_in[6];
  const float* bf = (const float*)d_in[7];
  const float* Wo = (const float*)d_in[8];
  const float* bo = (const float*)d_in[9];
  const float* Ww = (const float*)d_in[10];
  const float* bw = (const float*)d_in[11];
  const float* W1 = (const float*)d_in[12];
  const float* b1 = (const float*)d_in[13];
  const float* W2 = (const float*)d_in[14];
  const float* b2 = (const float*)d_in[15];
  float* out = (float*)d_out;

  // ws layout (bytes): qraw 67108864 | cov 262144 | ABt 262144 | W2t 131072 | u,v 2048
  char* ws = (char*)d_ws;
  ushort* qraw = (ushort*)ws;                         // [65536, 512] bf16
  float*  cov  = (float*)(ws + 67108864);             // [65536]
  ushort* ABt  = (ushort*)(ws + 67108864 + 262144);   // [256, 512] bf16
  ushort* W2t  = (ushort*)(ws + 67108864 + 524288);   // [256, 256] bf16
  float*  uvec = (float*)(ws + 67108864 + 655360);
  float*  vvec = uvec + 256;

  // d_out multi-duty (all overwritten by k_gemm2 at the end):
  //   [0 .. 8.39M floats)  fmT bf16 (16.77M ushorts)
  //   [9M .. 10.05M floats) proj [65536,16] f32
  ushort* fmT  = (ushort*)d_out;
  float*  proj = out + 9437184;

  k_transpose<<<2048, 256, 0, stream>>>(fm, fmT);
  k_prep<<<769, 256, 0, stream>>>(Wq, Wf, W1, W2, bq, bf, ABt, W2t, uvec, vvec);
  k_proj<<<4096, 256, 0, stream>>>(queries, valid, Wo, bo, Ww, bw, proj, qraw);
  k_gather<<<2048, 256, 0, stream>>>(proj, ref, valid, fmT, qraw, cov);
  k_gemm<512, 0><<<512, 512, 0, stream>>>(qraw, ABt, valid, cov, uvec, vvec, b1, qraw, nullptr);
  k_gemm<256, 1><<<512, 512, 0, stream>>>(qraw, W2t, valid, cov, uvec, vvec, b2, nullptr, out);
}

// Round 4
// 136.234 us; speedup vs baseline: 3.6844x; 1.3832x over previous
//
#include <hip/hip_runtime.h>
#include <hip/hip_bf16.h>
#include <math.h>

// CVFusionProposalRefiner on MI355X — round 4.
// Pipeline:
//   1) k_misc:   [blocks 0..2048)   transpose fm -> fmT bf16 (d_out)
//                [2048..2817)       prep ABt/W2t bf16 + u/v fp32 (ws)
//                [2817..6913)       proj = q@[Wo|Ww]+b (d_out) + masked bf16 q -> qraw[:, :256]
//   2) k_gather: 4 queries/wave, branchless bilinear bf16 gather -> qraw[:, 256:], cov
//   3) k_gemm_fused: h = relu(qraw@ABt^T + m*u + cov*v + b1) -> LDS (bf16, swizzled)
//                    out = h@W2t^T + b2 -> fp32 d_out          (one kernel, M-tile 64)

#define NQ 65536
#define OFFSET_SCALE 0.05f

typedef __bf16 bf16x8 __attribute__((ext_vector_type(8)));
typedef float f32x4 __attribute__((ext_vector_type(4)));
typedef float f32x2 __attribute__((ext_vector_type(2)));

__device__ __forceinline__ float dot4(float4 a, float4 b) {
  return a.x * b.x + a.y * b.y + a.z * b.z + a.w * b.w;
}

__device__ __forceinline__ ushort f2bf(float f) {
  union { float f; unsigned u; } v; v.f = f;
  unsigned r = v.u + 0x7FFFu + ((v.u >> 16) & 1u);   // RNE
  return (ushort)(r >> 16);
}

__device__ __forceinline__ f32x2 up2(unsigned u) {
  union { unsigned u; float f; } lo, hi;
  lo.u = u << 16;
  hi.u = u & 0xFFFF0000u;
  f32x2 r = {lo.f, hi.f};
  return r;
}

__device__ __forceinline__ unsigned pkbf(f32x2 v) {
  float2 f; f.x = v[0]; f.y = v[1];
  union { __hip_bfloat162 h; unsigned u; } x;
  x.h = __float22bfloat162_rn(f);
  return x.u;
}

__device__ __forceinline__ void gload16(const void* g, void* s) {
  __builtin_amdgcn_global_load_lds(
      (const __attribute__((address_space(1))) void*)g,
      (__attribute__((address_space(3))) void*)s, 16, 0, 0);
}

// ---------------- 1) misc: transpose | prep | proj -------------------------
__global__ void __launch_bounds__(256) k_misc(
    const float* __restrict__ fm, ushort* __restrict__ fmT,
    const float* __restrict__ Wq, const float* __restrict__ Wf,
    const float* __restrict__ W1, const float* __restrict__ W2,
    const float* __restrict__ bq, const float* __restrict__ bf,
    ushort* __restrict__ ABt, ushort* __restrict__ W2t,
    float* __restrict__ uvec, float* __restrict__ vvec,
    const float* __restrict__ queries, const int* __restrict__ valid,
    const float* __restrict__ Wo, const float* __restrict__ bo,
    const float* __restrict__ Ww, const float* __restrict__ bw,
    float* __restrict__ proj, ushort* __restrict__ qraw) {
  __shared__ float smem[128 * 65];
  const int bid = blockIdx.x;
  const int t = threadIdx.x;

  if (bid < 2048) {                       // ---- transpose ----
    const int c0 = (bid & 3) * 64;
    const int y  = (bid >> 2) & 127;
    const int b  = bid >> 9;
    float (*tile)[65] = (float(*)[65])smem;
    for (int idx = t; idx < 64 * 128; idx += 256) {
      const int ci = idx >> 7, x = idx & 127;
      tile[x][ci] = fm[(((size_t)(b * 256 + c0 + ci) * 128 + y) << 7) + x];
    }
    __syncthreads();
    for (int idx = t; idx < 128 * 16; idx += 256) {
      const int x = idx >> 4, cg = idx & 15;
      ushort4 o;
      o.x = f2bf(tile[x][cg * 4 + 0]);
      o.y = f2bf(tile[x][cg * 4 + 1]);
      o.z = f2bf(tile[x][cg * 4 + 2]);
      o.w = f2bf(tile[x][cg * 4 + 3]);
      *(ushort4*)(fmT + (((size_t)((b * 128 + y) * 128 + x)) << 8) + c0 + cg * 4) = o;
    }
  } else if (bid < 2817) {                // ---- prep ----
    const int blk = bid - 2048;
    const int n = t;
    if (blk < 256) {
      float s = 0.f;
      for (int j = 0; j < 256; ++j) s = fmaf(Wq[blk * 256 + j], W1[j * 256 + n], s);
      ABt[(size_t)n * 512 + blk] = f2bf(s);
    } else if (blk < 512) {
      const int k = blk - 256;
      float s = 0.f;
      for (int j = 0; j < 256; ++j) s = fmaf(Wf[k * 256 + j], W1[(256 + j) * 256 + n], s);
      ABt[(size_t)n * 512 + 256 + k] = f2bf(s);
    } else if (blk == 512) {
      float su = 0.f, sv = 0.f;
      for (int j = 0; j < 256; ++j) {
        su = fmaf(bq[j], W1[j * 256 + n], su);
        sv = fmaf(bf[j], W1[(256 + j) * 256 + n], sv);
      }
      uvec[n] = su;
      vvec[n] = sv;
    } else {
      const int k = blk - 513;
      W2t[(size_t)n * 256 + k] = f2bf(W2[(size_t)k * 256 + n]);
    }
  } else {                                // ---- proj ----
    const int blk = bid - 2817;
    float (*sW)[260] = (float(*)[260])smem;
    float* sb = smem + 12 * 260;
    for (int i = t; i < 2048; i += 256) sW[i & 7][i >> 3] = Wo[i];
    for (int i = t; i < 1024; i += 256) sW[8 + (i & 3)][i >> 2] = Ww[i];
    if (t < 8) sb[t] = bo[t];
    else if (t < 12) sb[t] = bw[t - 8];
    __syncthreads();

    const int lane = t & 63, wv = t >> 6;
    const int ql = lane >> 4, kc = lane & 15;
    const int qi = blk * 16 + wv * 4 + ql;
    const float mf = (valid[qi] != 0) ? 1.0f : 0.0f;

    float4 qv[4];
#pragma unroll
    for (int i = 0; i < 4; ++i)
      qv[i] = *(const float4*)(queries + (size_t)qi * 256 + kc * 4 + i * 64);

    float pr[12];
#pragma unroll
    for (int j = 0; j < 12; ++j) {
      float s = 0.f;
#pragma unroll
      for (int i = 0; i < 4; ++i)
        s += dot4(qv[i], *(const float4*)&sW[j][kc * 4 + i * 64]);
      pr[j] = s;
    }
#pragma unroll
    for (int m = 1; m < 16; m <<= 1) {
#pragma unroll
      for (int j = 0; j < 12; ++j) pr[j] += __shfl_xor(pr[j], m, 64);
    }
    if (kc == 0) {
      float4* pp = (float4*)(proj + (size_t)qi * 16);
      const float4 o0 = {pr[0] + sb[0], pr[1] + sb[1], pr[2] + sb[2],  pr[3] + sb[3]};
      const float4 o1 = {pr[4] + sb[4], pr[5] + sb[5], pr[6] + sb[6],  pr[7] + sb[7]};
      const float4 o2 = {pr[8] + sb[8], pr[9] + sb[9], pr[10] + sb[10], pr[11] + sb[11]};
      pp[0] = o0; pp[1] = o1; pp[2] = o2;
    }
#pragma unroll
    for (int i = 0; i < 4; ++i) {
      ushort4 h;
      h.x = f2bf(qv[i].x * mf); h.y = f2bf(qv[i].y * mf);
      h.z = f2bf(qv[i].z * mf); h.w = f2bf(qv[i].w * mf);
      *(ushort4*)(qraw + (size_t)qi * 512 + kc * 4 + i * 64) = h;
    }
  }
}

// ---------------- 2) gather: 4 queries/wave, branchless, packed ------------
__global__ void __launch_bounds__(256) k_gather(
    const float* __restrict__ proj, const float* __restrict__ ref,
    const int* __restrict__ valid, const ushort* __restrict__ fmT,
    ushort* __restrict__ qraw, float* __restrict__ cov) {
  const int t = threadIdx.x, lane = t & 63, wv = t >> 6;
  const int qs = lane >> 4;            // query slot within wave
  const int kc = lane & 15;            // channel group (8 ch per half)
  const int xcd = blockIdx.x & 7;
  const int b = xcd >> 1;
  const int p = ((blockIdx.x >> 3) << 1) | (xcd & 1);   // 0..511 within batch
  const ushort* fmTb = fmT + ((size_t)b << 22);

#pragma unroll 1
  for (int it = 0; it < 2; ++it) {
    const int qi = b * 16384 + it * 8192 + p * 16 + wv * 4 + qs;
    const float mf = (valid[qi] != 0) ? 1.0f : 0.0f;
    const float4 pA = *(const float4*)(proj + (size_t)qi * 16);
    const float4 pB = *(const float4*)(proj + (size_t)qi * 16 + 4);
    const float4 pC = *(const float4*)(proj + (size_t)qi * 16 + 8);
    const float rx = ref[qi * 2], ry = ref[qi * 2 + 1];

    const float po[8] = {pA.x, pA.y, pA.z, pA.w, pB.x, pB.y, pB.z, pB.w};
    float o[8];
#pragma unroll
    for (int j = 0; j < 8; ++j) {
      const float x = po[j];
      const float e = __expf(2.0f * fabsf(x));
      const float th = 1.0f - 2.0f * __builtin_amdgcn_rcpf(e + 1.0f);
      o[j] = copysignf(th, x) * OFFSET_SCALE;
    }
    float wl[4] = {pC.x, pC.y, pC.z, pC.w};
    const float wmax = fmaxf(fmaxf(wl[0], wl[1]), fmaxf(wl[2], wl[3]));
    float wsum = 0.f;
#pragma unroll
    for (int j = 0; j < 4; ++j) { wl[j] = __expf(wl[j] - wmax); wsum += wl[j]; }
    const float winv = mf * __builtin_amdgcn_rcpf(wsum);

    f32x2 acc[8] = {};
    float cv = 0.f;

#define CORN(PIXPTR, CF)                                                     \
    do {                                                                     \
      const float cfv = (CF);                                                \
      const uint4 u0 = *(const uint4*)((PIXPTR) + kc * 8);                   \
      const uint4 u1 = *(const uint4*)((PIXPTR) + kc * 8 + 128);             \
      const f32x2 c2 = {cfv, cfv};                                           \
      acc[0] += c2 * up2(u0.x); acc[1] += c2 * up2(u0.y);                    \
      acc[2] += c2 * up2(u0.z); acc[3] += c2 * up2(u0.w);                    \
      acc[4] += c2 * up2(u1.x); acc[5] += c2 * up2(u1.y);                    \
      acc[6] += c2 * up2(u1.z); acc[7] += c2 * up2(u1.w);                    \
    } while (0)

#pragma unroll
    for (int s = 0; s < 4; ++s) {
      const float wgt = wl[s] * winv;
      const float gx = fminf(fmaxf(rx + o[2 * s],     -1.2f), 1.2f);
      const float gy = fminf(fmaxf(ry + o[2 * s + 1], -1.2f), 1.2f);
      const float xf = (gx + 1.0f) * 63.5f;
      const float yf = (gy + 1.0f) * 63.5f;
      const float x0f = floorf(xf), y0f = floorf(yf);
      const float wx = xf - x0f, wy = yf - y0f;
      const int x0 = (int)x0f, y0 = (int)y0f;
      const float wx0 = ((unsigned)x0 < 128u) ? (1.0f - wx) : 0.0f;
      const float wx1 = ((unsigned)(x0 + 1) < 128u) ? wx : 0.0f;
      const float wy0 = ((unsigned)y0 < 128u) ? (wgt * (1.0f - wy)) : 0.0f;
      const float wy1 = ((unsigned)(y0 + 1) < 128u) ? (wgt * wy) : 0.0f;
      const int xc0 = min(max(x0, 0), 127), xc1 = min(max(x0 + 1, 0), 127);
      const int yc0 = min(max(y0, 0), 127), yc1 = min(max(y0 + 1, 0), 127);
      cv += (wx0 + wx1) * (wy0 + wy1);
      const ushort* r0 = fmTb + ((size_t)yc0 << 15);   // yc0*128*256
      const ushort* r1 = fmTb + ((size_t)yc1 << 15);
      CORN(r0 + (xc0 << 8), wy0 * wx0);
      CORN(r0 + (xc1 << 8), wy0 * wx1);
      CORN(r1 + (xc0 << 8), wy1 * wx0);
      CORN(r1 + (xc1 << 8), wy1 * wx1);
    }
#undef CORN

    uint4 w0, w1;
    w0.x = pkbf(acc[0]); w0.y = pkbf(acc[1]); w0.z = pkbf(acc[2]); w0.w = pkbf(acc[3]);
    w1.x = pkbf(acc[4]); w1.y = pkbf(acc[5]); w1.z = pkbf(acc[6]); w1.w = pkbf(acc[7]);
    *(uint4*)(qraw + (size_t)qi * 512 + 256 + kc * 8) = w0;
    *(uint4*)(qraw + (size_t)qi * 512 + 256 + 128 + kc * 8) = w1;
    if (kc == 0) cov[qi] = cv;
  }
}

// ---------------- 3) fused GEMM1+GEMM2, M-tile 64, 4 waves -----------------
// phase 1: h[64,256] = relu(qraw[64,512] @ ABt^T + m*u + cov*v + b1) -> Hs (LDS)
// phase 2: out[64,256] = Hs @ W2t^T + b2 -> fp32
__global__ void __launch_bounds__(256, 3) k_gemm_fused(
    const ushort* __restrict__ qraw, const ushort* __restrict__ ABt,
    const ushort* __restrict__ W2t, const int* __restrict__ valid,
    const float* __restrict__ cov, const float* __restrict__ uvec,
    const float* __restrict__ vvec, const float* __restrict__ b1,
    const float* __restrict__ b2, float* __restrict__ out) {
  __shared__ ushort As[64 * 32];      // 4 KB
  __shared__ ushort Bs[256 * 32];     // 16 KB
  __shared__ ushort Hs[64 * 256];     // 32 KB, slot-XOR swizzled
  const int t = threadIdx.x;
  const int m0 = blockIdx.x * 64;
  const int wn = t >> 6, lane = t & 63;
  const int lr = lane & 15, lg = lane >> 4;

  const int srow = t >> 2;
  const int schunk = ((t & 3) ^ ((srow >> 1) & 3)) * 8;  // pre-swizzled source chunk
  const int swz = (lg ^ ((lr >> 1) & 3)) * 8;            // swizzled read offset

  const ushort* ag = qraw + (size_t)(m0 + srow) * 512 + schunk;
  const ushort* bg = ABt + (size_t)srow * 512 + schunk;
  ushort* la = As + t * 8;
  ushort* lb = Bs + t * 8;

  f32x4 acc[4][4] = {};

  // ---- phase 1: K = 512 ----
  for (int k0 = 0; k0 < 512; k0 += 32) {
    __syncthreads();
    gload16(ag + k0, la);
    gload16(bg + k0, lb);
    gload16(bg + 64 * 512 + k0, lb + 2048);
    gload16(bg + 128 * 512 + k0, lb + 4096);
    gload16(bg + 192 * 512 + k0, lb + 6144);
    __syncthreads();
    bf16x8 af[4], bfr[4];
#pragma unroll
    for (int m = 0; m < 4; ++m)
      af[m] = *(const bf16x8*)(As + (m * 16 + lr) * 32 + swz);
#pragma unroll
    for (int n = 0; n < 4; ++n)
      bfr[n] = *(const bf16x8*)(Bs + (wn * 64 + n * 16 + lr) * 32 + swz);
#pragma unroll
    for (int m = 0; m < 4; ++m)
#pragma unroll
      for (int n = 0; n < 4; ++n)
        acc[m][n] = __builtin_amdgcn_mfma_f32_16x16x32_bf16(af[m], bfr[n], acc[m][n], 0, 0, 0);
  }

  // ---- epilogue 1 -> Hs (bf16, swizzled) ----
  {
    float uu[4], vv[4], bb[4];
#pragma unroll
    for (int n = 0; n < 4; ++n) {
      const int col = wn * 64 + n * 16 + lr;
      uu[n] = uvec[col]; vv[n] = vvec[col]; bb[n] = b1[col];
    }
#pragma unroll
    for (int m = 0; m < 4; ++m)
#pragma unroll
      for (int j = 0; j < 4; ++j) {
        const int row = m * 16 + lg * 4 + j;      // local row
        const float mfv = valid[m0 + row] ? 1.0f : 0.0f;
        const float cvr = cov[m0 + row];
#pragma unroll
        for (int n = 0; n < 4; ++n) {
          const int col = wn * 64 + n * 16 + lr;
          float r = acc[m][n][j] + mfv * uu[n] + cvr * vv[n] + bb[n];
          r = fmaxf(r, 0.0f);
          const int slot = (col >> 3) ^ (row & 7);
          Hs[row * 256 + slot * 8 + (col & 7)] = f2bf(r);
        }
      }
  }

  // ---- phase 2: K = 256, A = Hs, B = W2t ----
  const ushort* cg = W2t + (size_t)srow * 256 + schunk;
#pragma unroll
  for (int m = 0; m < 4; ++m)
#pragma unroll
    for (int n = 0; n < 4; ++n) {
      f32x4 z = {0.f, 0.f, 0.f, 0.f};
      acc[m][n] = z;
    }

  for (int k0 = 0; k0 < 256; k0 += 32) {
    __syncthreads();
    gload16(cg + k0, lb);
    gload16(cg + 64 * 256 + k0, lb + 2048);
    gload16(cg + 128 * 256 + k0, lb + 4096);
    gload16(cg + 192 * 256 + k0, lb + 6144);
    __syncthreads();
    bf16x8 af[4], bfr[4];
#pragma unroll
    for (int m = 0; m < 4; ++m) {
      const int slot = ((k0 >> 3) + lg) ^ (lr & 7);
      af[m] = *(const bf16x8*)(Hs + (m * 16 + lr) * 256 + slot * 8);
    }
#pragma unroll
    for (int n = 0; n < 4; ++n)
      bfr[n] = *(const bf16x8*)(Bs + (wn * 64 + n * 16 + lr) * 32 + swz);
#pragma unroll
    for (int m = 0; m < 4; ++m)
#pragma unroll
      for (int n = 0; n < 4; ++n)
        acc[m][n] = __builtin_amdgcn_mfma_f32_16x16x32_bf16(af[m], bfr[n], acc[m][n], 0, 0, 0);
  }

  // ---- epilogue 2 -> out fp32 ----
  {
    float bb[4];
#pragma unroll
    for (int n = 0; n < 4; ++n) bb[n] = b2[wn * 64 + n * 16 + lr];
#pragma unroll
    for (int m = 0; m < 4; ++m)
#pragma unroll
      for (int j = 0; j < 4; ++j) {
        const int row = m0 + m * 16 + lg * 4 + j;
#pragma unroll
        for (int n = 0; n < 4; ++n)
          out[(size_t)row * 256 + wn * 64 + n * 16 + lr] = acc[m][n][j] + bb[n];
      }
  }
}

extern "C" void kernel_launch(void* const* d_in, const int* in_sizes, int n_in,
                              void* d_out, int out_size, void* d_ws, size_t ws_size,
                              hipStream_t stream) {
  const float* queries = (const float*)d_in[0];
  const float* ref     = (const float*)d_in[1];
  const float* fm      = (const float*)d_in[2];
  const int*   valid   = (const int*)d_in[3];
  const float* Wq = (const float*)d_in[4];
  const float* bq = (const float*)d_in[5];
  const float* Wf = (const float*)d_in[6];
  const float* bf = (const float*)d_in[7];
  const float* Wo = (const float*)d_in[8];
  const float* bo = (const float*)d_in[9];
  const float* Ww = (const float*)d_in[10];
  const float* bw = (const float*)d_in[11];
  const float* W1 = (const float*)d_in[12];
  const float* b1 = (const float*)d_in[13];
  const float* W2 = (const float*)d_in[14];
  const float* b2 = (const float*)d_in[15];
  float* out = (float*)d_out;

  // ws layout (bytes): qraw 67108864 | cov 262144 | ABt 262144 | W2t 131072 | u,v 2048
  char* ws = (char*)d_ws;
  ushort* qraw = (ushort*)ws;                         // [65536, 512] bf16
  float*  cov  = (float*)(ws + 67108864);             // [65536]
  ushort* ABt  = (ushort*)(ws + 67108864 + 262144);   // [256, 512] bf16
  ushort* W2t  = (ushort*)(ws + 67108864 + 524288);   // [256, 256] bf16
  float*  uvec = (float*)(ws + 67108864 + 655360);
  float*  vvec = uvec + 256;

  // d_out multi-duty (all regions dead before k_gemm_fused writes out):
  //   floats [0 .. 8388608)        fmT bf16 (16.77M ushorts)
  //   floats [9437184 .. 10485760) proj [65536,16] f32
  ushort* fmT  = (ushort*)d_out;
  float*  proj = out + 9437184;

  k_misc<<<6913, 256, 0, stream>>>(fm, fmT, Wq, Wf, W1, W2, bq, bf, ABt, W2t,
                                   uvec, vvec, queries, valid, Wo, bo, Ww, bw,
                                   proj, qraw);
  k_gather<<<2048, 256, 0, stream>>>(proj, ref, valid, fmT, qraw, cov);
  k_gemm_fused<<<1024, 256, 0, stream>>>(qraw, ABt, W2t, valid, cov, uvec, vvec,
                                         b1, b2, out);
}